// Round 9
// baseline (452.416 us; speedup 1.0000x reference)
//
#include <hip/hip_runtime.h>

#define NEG_SLOPE 0.2f
#define CAP 64  // bucket capacity per node; overflow handled exactly

// ---------------------------------------------------------------------------
__global__ void zero_kernel(int* __restrict__ p, int n) {
    int i = blockIdx.x * blockDim.x + threadIdx.x;
    if (i < n) p[i] = 0;
}

// ---------------------------------------------------------------------------
// One-pass adjacency build. 4 edges per thread (grid-stride) => 4 independent
// atomicAdd->store chains in flight per lane (the single-edge version was
// latency-bound: VALUBusy 2.2%, 85ns/edge serial chain).
// ---------------------------------------------------------------------------
__global__ void build_kernel(const void* __restrict__ ei_raw, int E,
                             int* __restrict__ cnt, int* __restrict__ bucket,
                             int* __restrict__ ovf_src,
                             int* __restrict__ ovf_dst,
                             int* __restrict__ ovf_cnt) {
    const int* as32 = (const int*)ei_raw;
    const long long* as64 = (const long long*)ei_raw;
    bool is64 = true;
    for (int i = 0; i < 16; ++i) {
        long long v = as64[i];
        if (!(v >= 0 && v < 2147483648LL)) { is64 = false; }
    }
    int stride = gridDim.x * blockDim.x;
    int i0 = blockIdx.x * blockDim.x + threadIdx.x;
#pragma unroll
    for (int u = 0; u < 4; ++u) {
        int i = i0 + u * stride;
        if (i < E) {
            int s, d;
            if (is64) {
                s = (int)as64[i];
                d = (int)as64[(size_t)E + i];
            } else {
                s = as32[i];
                d = as32[(size_t)E + i];
            }
            int p = atomicAdd(&cnt[d], 1);
            if (p < CAP) {
                bucket[(size_t)d * CAP + p] = s;
            } else {
                int q = atomicAdd(ovf_cnt, 1);
                ovf_src[q] = s;
                ovf_dst[q] = d;
            }
        }
    }
}

// ---------------------------------------------------------------------------
// GEMM + fused alpha epilogue. 256 threads; 64 rows x 128 cols per block;
// thread tile 4 rows x 8 cols; X and W staged in LDS.
// ---------------------------------------------------------------------------
template <int H>
__global__ __launch_bounds__(256) void gemm128_kernel(
    const float* __restrict__ X, const float* __restrict__ W,
    const float* __restrict__ asrc, const float* __restrict__ adst,
    float* __restrict__ Hout, float* __restrict__ alpha_s,
    float* __restrict__ alpha_d, int N) {
    __shared__ float sX[64 * 132];
    __shared__ float sW[64 * 132];
    int t = threadIdx.x;
    int tx = t & 15;
    int ty = t >> 4;
    int row0 = blockIdx.x * 64;

    const float4* X4 = (const float4*)X;
#pragma unroll
    for (int it = 0; it < 8; ++it) {
        int idx = t + it * 256;
        int r = idx >> 5;
        int q = idx & 31;
        int row = row0 + r;
        float4 v = make_float4(0.f, 0.f, 0.f, 0.f);
        if (row < N) v = X4[(size_t)row * 32 + q];
        *(float4*)&sX[r * 132 + q * 4] = v;
    }

    float acc[4][8] = {};
    const float4* W4 = (const float4*)W;

    for (int p = 0; p < 2; ++p) {
#pragma unroll
        for (int it = 0; it < 8; ++it) {
            int idx = t + it * 256;
            int kk = idx >> 5;
            int q = idx & 31;
            float4 v = W4[(p * 64 + kk) * 32 + q];
            *(float4*)&sW[kk * 132 + q * 4] = v;
        }
        __syncthreads();

        for (int k4 = 0; k4 < 64; k4 += 4) {
            float4 a[4];
#pragma unroll
            for (int i = 0; i < 4; ++i)
                a[i] = *(const float4*)&sX[(i * 16 + ty) * 132 + p * 64 + k4];
#pragma unroll
            for (int kk = 0; kk < 4; ++kk) {
                float4 b0 = *(const float4*)&sW[(k4 + kk) * 132 + tx * 8];
                float4 b1 = *(const float4*)&sW[(k4 + kk) * 132 + tx * 8 + 4];
#pragma unroll
                for (int i = 0; i < 4; ++i) {
                    float av = ((const float*)&a[i])[kk];
                    acc[i][0] += av * b0.x;
                    acc[i][1] += av * b0.y;
                    acc[i][2] += av * b0.z;
                    acc[i][3] += av * b0.w;
                    acc[i][4] += av * b1.x;
                    acc[i][5] += av * b1.y;
                    acc[i][6] += av * b1.z;
                    acc[i][7] += av * b1.w;
                }
            }
        }
        __syncthreads();
    }

#pragma unroll
    for (int i = 0; i < 4; ++i) {
        int row = row0 + i * 16 + ty;
        if (row < N) {
            float4 o0 = make_float4(acc[i][0], acc[i][1], acc[i][2], acc[i][3]);
            float4 o1 = make_float4(acc[i][4], acc[i][5], acc[i][6], acc[i][7]);
            ((float4*)Hout)[(size_t)row * 32 + tx * 2] = o0;
            ((float4*)Hout)[(size_t)row * 32 + tx * 2 + 1] = o1;
        }
    }

    constexpr int RW = (H == 4) ? 4 : 16;  // tx lanes per head (C/8)
    float4 av0 = ((const float4*)asrc)[tx * 2];
    float4 av1 = ((const float4*)asrc)[tx * 2 + 1];
    float4 dv0 = ((const float4*)adst)[tx * 2];
    float4 dv1 = ((const float4*)adst)[tx * 2 + 1];
#pragma unroll
    for (int i = 0; i < 4; ++i) {
        float ps = acc[i][0] * av0.x + acc[i][1] * av0.y + acc[i][2] * av0.z +
                   acc[i][3] * av0.w + acc[i][4] * av1.x + acc[i][5] * av1.y +
                   acc[i][6] * av1.z + acc[i][7] * av1.w;
        float pd = acc[i][0] * dv0.x + acc[i][1] * dv0.y + acc[i][2] * dv0.z +
                   acc[i][3] * dv0.w + acc[i][4] * dv1.x + acc[i][5] * dv1.y +
                   acc[i][6] * dv1.z + acc[i][7] * dv1.w;
#pragma unroll
        for (int o = 1; o < RW; o <<= 1) {
            ps += __shfl_xor(ps, o);
            pd += __shfl_xor(pd, o);
        }
        if ((tx & (RW - 1)) == 0) {
            int row = row0 + i * 16 + ty;
            if (row < N) {
                int hh = tx / RW;
                alpha_s[(size_t)row * H + hh] = ps;
                alpha_d[(size_t)row * H + hh] = pd;
            }
        }
    }
}

// ---------------------------------------------------------------------------
// Segment softmax + aggregation from the bucket table. Two nodes per wave
// (32 lanes each). Edge idx 0 = self-loop; idx 1..deg from bucket (first CAP)
// and the exact overflow list (deg>CAP only). Phase C x4 unroll (x8 raised
// VGPR 28->48, occupancy 67->44% -- net negative, R8).
// ---------------------------------------------------------------------------
template <int H>
__global__ __launch_bounds__(128) void gather_kernel(
    const float* __restrict__ h, const float* __restrict__ as_,
    const float* __restrict__ ad_, const int* __restrict__ cnt,
    const int* __restrict__ bucket, const int* __restrict__ ovf_src,
    const int* __restrict__ ovf_dst, const int* __restrict__ ovf_cnt,
    const float* __restrict__ bias, float* __restrict__ out, int N) {
    __shared__ int s_src[4][32];
    __shared__ float s_w[4][32 * H];
    int t = threadIdx.x;
    int wv = t >> 6;
    int lane = t & 63;
    int hw = lane >> 5;
    int l = lane & 31;
    int sub = wv * 2 + hw;
    int n = blockIdx.x * 4 + sub;
    if (n >= N) return;

    int deg = cnt[n];
    int total = deg + 1;                 // + self loop
    int totalb = min(deg, CAP) + 1;      // edges reachable via bucket
    int onum = (deg > CAP) ? *ovf_cnt : 0;  // nonzero only for overflow nodes
    const int* bk = bucket + (size_t)n * CAP;

    float adv[H];
#pragma unroll
    for (int hh = 0; hh < H; ++hh) adv[hh] = ad_[(size_t)n * H + hh];

    // Phase A: first 32 edges -> registers; stage src; per-head max
    float sv[H];
    float m[H];
#pragma unroll
    for (int hh = 0; hh < H; ++hh) m[hh] = -3.4e38f;
    int total0 = min(total, 32);
    if (l < total0) {
        int src = (l == 0) ? n : bk[l - 1];
        s_src[sub][l] = src;
        if (H == 4) {
            float4 a4 = ((const float4*)as_)[src];
            sv[0] = a4.x + adv[0];
            sv[1] = a4.y + adv[1];
            sv[2] = a4.z + adv[2];
            sv[3] = a4.w + adv[3];
        } else {
            sv[0] = as_[src] + adv[0];
        }
#pragma unroll
        for (int hh = 0; hh < H; ++hh) {
            float s = sv[hh];
            s = (s > 0.f) ? s : NEG_SLOPE * s;
            sv[hh] = s;
            m[hh] = s;
        }
    }
    for (int idx = l + 32; idx < totalb; idx += 32) {  // deg>31 fallback
        int src = bk[idx - 1];
#pragma unroll
        for (int hh = 0; hh < H; ++hh) {
            float s = as_[(size_t)src * H + hh] + adv[hh];
            s = (s > 0.f) ? s : NEG_SLOPE * s;
            m[hh] = fmaxf(m[hh], s);
        }
    }
    for (int e = 0; e < onum; ++e) {  // exact overflow path (deg>CAP only)
        if (ovf_dst[e] == n && l == 0) {
            int src = ovf_src[e];
#pragma unroll
            for (int hh = 0; hh < H; ++hh) {
                float s = as_[(size_t)src * H + hh] + adv[hh];
                s = (s > 0.f) ? s : NEG_SLOPE * s;
                m[hh] = fmaxf(m[hh], s);
            }
        }
    }
#pragma unroll
    for (int o = 16; o > 0; o >>= 1)
#pragma unroll
        for (int hh = 0; hh < H; ++hh) m[hh] = fmaxf(m[hh], __shfl_xor(m[hh], o));

    // Phase B: sum of exp
    float p[H];
    float dsum[H];
#pragma unroll
    for (int hh = 0; hh < H; ++hh) dsum[hh] = 0.f;
    if (l < total0) {
#pragma unroll
        for (int hh = 0; hh < H; ++hh) {
            p[hh] = __expf(sv[hh] - m[hh]);
            dsum[hh] = p[hh];
        }
    }
    for (int idx = l + 32; idx < totalb; idx += 32) {
        int src = bk[idx - 1];
#pragma unroll
        for (int hh = 0; hh < H; ++hh) {
            float s = as_[(size_t)src * H + hh] + adv[hh];
            s = (s > 0.f) ? s : NEG_SLOPE * s;
            dsum[hh] += __expf(s - m[hh]);
        }
    }
    for (int e = 0; e < onum; ++e) {
        if (ovf_dst[e] == n && l == 0) {
            int src = ovf_src[e];
#pragma unroll
            for (int hh = 0; hh < H; ++hh) {
                float s = as_[(size_t)src * H + hh] + adv[hh];
                s = (s > 0.f) ? s : NEG_SLOPE * s;
                dsum[hh] += __expf(s - m[hh]);
            }
        }
    }
#pragma unroll
    for (int o = 16; o > 0; o >>= 1)
#pragma unroll
        for (int hh = 0; hh < H; ++hh) dsum[hh] += __shfl_xor(dsum[hh], o);
    float inv[H];
#pragma unroll
    for (int hh = 0; hh < H; ++hh) inv[hh] = 1.f / dsum[hh];

    if (l < total0) {
#pragma unroll
        for (int hh = 0; hh < H; ++hh) s_w[sub][l * H + hh] = p[hh] * inv[hh];
    }

    // Phase C: weighted accumulation; lane owns channels 4l..4l+3 (one head)
    const int head_t = (H == 1) ? 0 : (l >> 3);
    float4 acc = make_float4(0.f, 0.f, 0.f, 0.f);
    const float4* __restrict__ h4 = (const float4*)h;
    for (int base = 0; base < totalb; base += 32) {
        int cnt2 = min(32, totalb - base);
        if (base > 0 && l < cnt2) {  // restage (deg>31 fallback)
            int src = bk[base + l - 1];
            s_src[sub][l] = src;
#pragma unroll
            for (int hh = 0; hh < H; ++hh) {
                float s = as_[(size_t)src * H + hh] + adv[hh];
                s = (s > 0.f) ? s : NEG_SLOPE * s;
                s_w[sub][l * H + hh] = __expf(s - m[hh]) * inv[hh];
            }
        }
        __builtin_amdgcn_wave_barrier();
        int j = 0;
        for (; j + 4 <= cnt2; j += 4) {
            int t0 = s_src[sub][j + 0], t1 = s_src[sub][j + 1];
            int t2 = s_src[sub][j + 2], t3 = s_src[sub][j + 3];
            float w0 = s_w[sub][(j + 0) * H + head_t];
            float w1 = s_w[sub][(j + 1) * H + head_t];
            float w2 = s_w[sub][(j + 2) * H + head_t];
            float w3 = s_w[sub][(j + 3) * H + head_t];
            float4 v0 = h4[(size_t)t0 * 32 + l];
            float4 v1 = h4[(size_t)t1 * 32 + l];
            float4 v2 = h4[(size_t)t2 * 32 + l];
            float4 v3 = h4[(size_t)t3 * 32 + l];
            acc.x += w0 * v0.x; acc.y += w0 * v0.y;
            acc.z += w0 * v0.z; acc.w += w0 * v0.w;
            acc.x += w1 * v1.x; acc.y += w1 * v1.y;
            acc.z += w1 * v1.z; acc.w += w1 * v1.w;
            acc.x += w2 * v2.x; acc.y += w2 * v2.y;
            acc.z += w2 * v2.z; acc.w += w2 * v2.w;
            acc.x += w3 * v3.x; acc.y += w3 * v3.y;
            acc.z += w3 * v3.z; acc.w += w3 * v3.w;
        }
        for (; j < cnt2; ++j) {
            int sj = s_src[sub][j];
            float wj = s_w[sub][j * H + head_t];
            float4 hv = h4[(size_t)sj * 32 + l];
            acc.x += wj * hv.x; acc.y += wj * hv.y;
            acc.z += wj * hv.z; acc.w += wj * hv.w;
        }
        __builtin_amdgcn_wave_barrier();
    }
    for (int e = 0; e < onum; ++e) {  // exact overflow accumulate
        if (ovf_dst[e] == n) {
            int src = ovf_src[e];
            int hh = head_t;
            float s = as_[(size_t)src * H + hh] + adv[hh];
            s = (s > 0.f) ? s : NEG_SLOPE * s;
            float wj = __expf(s - m[hh]) * inv[hh];
            float4 hv = h4[(size_t)src * 32 + l];
            acc.x += wj * hv.x; acc.y += wj * hv.y;
            acc.z += wj * hv.z; acc.w += wj * hv.w;
        }
    }
    float4 bv = ((const float4*)bias)[l];
    float4 o4;
    o4.x = fmaxf(acc.x + bv.x, 0.f);
    o4.y = fmaxf(acc.y + bv.y, 0.f);
    o4.z = fmaxf(acc.z + bv.z, 0.f);
    o4.w = fmaxf(acc.w + bv.w, 0.f);
    ((float4*)out)[(size_t)n * 32 + l] = o4;
}

// ---------------------------------------------------------------------------
extern "C" void kernel_launch(void* const* d_in, const int* in_sizes, int n_in,
                              void* d_out, int out_size, void* d_ws,
                              size_t ws_size, hipStream_t stream) {
    const float* x   = (const float*)d_in[0];
    const void*  ei  = d_in[1];
    const float* W0  = (const float*)d_in[2];
    const float* as0 = (const float*)d_in[3];
    const float* ad0 = (const float*)d_in[4];
    const float* b0  = (const float*)d_in[5];
    const float* W1  = (const float*)d_in[6];
    const float* as1 = (const float*)d_in[7];
    const float* ad1 = (const float*)d_in[8];
    const float* b1  = (const float*)d_in[9];
    const float* W2  = (const float*)d_in[10];
    const float* as2 = (const float*)d_in[11];
    const float* ad2 = (const float*)d_in[12];
    const float* b2  = (const float*)d_in[13];

    int N = in_sizes[0] / 128;
    int E = in_sizes[1] / 2;
    float* out = (float*)d_out;

    // workspace layout (~47 MB)
    float* h       = (float*)d_ws;                       // N*128
    float* alpha_s = h + (size_t)N * 128;                // N*4 (max H)
    float* alpha_d = alpha_s + (size_t)N * 4;            // N*4
    int*   cnt     = (int*)(alpha_d + (size_t)N * 4);    // N
    int*   ovf_c   = cnt + N;                            // 1
    int*   bucket  = ovf_c + 1;                          // N*CAP
    int*   ovf_src = bucket + (size_t)N * CAP;           // E
    int*   ovf_dst = ovf_src + E;                        // E

    int nb = (N + 1 + 255) / 256;
    int bb = (E + 4 * 256 - 1) / (4 * 256);  // 4 edges per thread

    zero_kernel<<<nb, 256, 0, stream>>>(cnt, N + 1);  // cnt + ovf counter
    build_kernel<<<bb, 256, 0, stream>>>(ei, E, cnt, bucket, ovf_src, ovf_dst, ovf_c);

    int gb = (N + 63) / 64;
    int wb = (N + 3) / 4;  // 4 nodes per 128-thread block (2 per wave)

    // layer 0: H=4
    gemm128_kernel<4><<<gb, 256, 0, stream>>>(x, W0, as0, ad0, h, alpha_s, alpha_d, N);
    gather_kernel<4><<<wb, 128, 0, stream>>>(h, alpha_s, alpha_d, cnt, bucket,
                                             ovf_src, ovf_dst, ovf_c, b0, out, N);

    // layer 1: H=4
    gemm128_kernel<4><<<gb, 256, 0, stream>>>(out, W1, as1, ad1, h, alpha_s, alpha_d, N);
    gather_kernel<4><<<wb, 128, 0, stream>>>(h, alpha_s, alpha_d, cnt, bucket,
                                             ovf_src, ovf_dst, ovf_c, b1, out, N);

    // layer 2: H=1
    gemm128_kernel<1><<<gb, 256, 0, stream>>>(out, W2, as2, ad2, h, alpha_s, alpha_d, N);
    gather_kernel<1><<<wb, 128, 0, stream>>>(h, alpha_s, alpha_d, cnt, bucket,
                                             ovf_src, ovf_dst, ovf_c, b2, out, N);
}

// Round 10
// 408.891 us; speedup vs baseline: 1.1064x; 1.1064x over previous
//
#include <hip/hip_runtime.h>

#define NEG_SLOPE 0.2f
#define CAP 64  // bucket capacity per node; overflow handled exactly

using f32x4 = __attribute__((ext_vector_type(4))) float;
using bf16x8 = __attribute__((ext_vector_type(8))) short;

__device__ inline unsigned short bf16_rne(float f) {
    unsigned int u = __float_as_uint(f);
    return (unsigned short)((u + 0x7FFF + ((u >> 16) & 1)) >> 16);
}
__device__ inline float bf16_tof(unsigned short h) {
    return __uint_as_float(((unsigned int)h) << 16);
}

// ---------------------------------------------------------------------------
__global__ void zero_kernel(int* __restrict__ p, int n) {
    int i = blockIdx.x * blockDim.x + threadIdx.x;
    if (i < n) p[i] = 0;
}

// ---------------------------------------------------------------------------
// One-pass adjacency build (R8 version: 1 edge/thread, full grid — best
// measured: 68us; bound by per-CU scattered atomic+store issue rate).
// ---------------------------------------------------------------------------
__global__ void build_kernel(const void* __restrict__ ei_raw, int E,
                             int* __restrict__ cnt, int* __restrict__ bucket,
                             int* __restrict__ ovf_src,
                             int* __restrict__ ovf_dst,
                             int* __restrict__ ovf_cnt) {
    const int* as32 = (const int*)ei_raw;
    const long long* as64 = (const long long*)ei_raw;
    bool is64 = true;
    for (int i = 0; i < 16; ++i) {
        long long v = as64[i];
        if (!(v >= 0 && v < 2147483648LL)) { is64 = false; }
    }
    int i = blockIdx.x * blockDim.x + threadIdx.x;
    if (i < E) {
        int s, d;
        if (is64) {
            s = (int)as64[i];
            d = (int)as64[(size_t)E + i];
        } else {
            s = as32[i];
            d = as32[(size_t)E + i];
        }
        int p = atomicAdd(&cnt[d], 1);
        if (p < CAP) {
            bucket[(size_t)d * CAP + p] = s;
        } else {
            int q = atomicAdd(ovf_cnt, 1);
            ovf_src[q] = s;
            ovf_dst[q] = d;
        }
    }
}

// ---------------------------------------------------------------------------
// W pre-transform: fragment-ready bf16 hi/lo for the MFMA gemm.
// Layout per layer (32768 ushort): hi[(kstep*8+ct)*64+lane][8j] then lo at
// +16384. B-frag element: W[k=kstep*32+(lane>>4)*8+j][n=ct*16+(lane&15)].
// ---------------------------------------------------------------------------
__global__ void wprep_kernel(const float* __restrict__ W0,
                             const float* __restrict__ W1,
                             const float* __restrict__ W2,
                             unsigned short* __restrict__ wf) {
    int tid = blockIdx.x * blockDim.x + threadIdx.x;  // 0..6143
    if (tid >= 3 * 2048) return;
    int layer = tid >> 11;
    int rem = tid & 2047;
    int kstep = rem >> 9;
    int ct = (rem >> 6) & 7;
    int lane = rem & 63;
    const float* W = (layer == 0) ? W0 : (layer == 1) ? W1 : W2;
    unsigned short* hi = wf + (size_t)layer * 32768 +
                         ((size_t)(kstep * 8 + ct) * 64 + lane) * 8;
    unsigned short* lo = hi + 16384;
#pragma unroll
    for (int j = 0; j < 8; ++j) {
        int k = kstep * 32 + (lane >> 4) * 8 + j;
        int n = ct * 16 + (lane & 15);
        float f = W[k * 128 + n];
        unsigned short h = bf16_rne(f);
        hi[j] = h;
        lo[j] = bf16_rne(f - bf16_tof(h));
    }
}

// ---------------------------------------------------------------------------
// Split-bf16 MFMA GEMM + fused alpha epilogue. 256 threads = 4 waves; each
// wave computes 16 rows x 128 cols via 8 col-tiles of 16x16x32 MFMA, K=128
// in 4 steps. C = Ahi*Bhi + Alo*Bhi + Ahi*Blo (err ~1e-5). LDS-free:
// A frags from global (rows guarded), B frags from wprep arrays (L2).
// C/D layout: col=lane&15, row=(lane>>4)*4+reg.
// ---------------------------------------------------------------------------
template <int H>
__global__ __launch_bounds__(256) void gemm_mfma_kernel(
    const float* __restrict__ X, const unsigned short* __restrict__ wf_hi,
    const unsigned short* __restrict__ wf_lo, const float* __restrict__ asrc,
    const float* __restrict__ adst, float* __restrict__ Hout,
    float* __restrict__ alpha_s, float* __restrict__ alpha_d, int N) {
    int t = threadIdx.x;
    int wv = t >> 6;
    int l = t & 63;
    int m = l & 15;
    int quad = l >> 4;
    int row0 = blockIdx.x * 64 + wv * 16;

    f32x4 acc[8];
#pragma unroll
    for (int ct = 0; ct < 8; ++ct) acc[ct] = (f32x4){0.f, 0.f, 0.f, 0.f};

    int arow = row0 + m;
    bool okA = arow < N;
    const float4* X4 = (const float4*)X;

    for (int kstep = 0; kstep < 4; ++kstep) {
        float4 a0 = make_float4(0.f, 0.f, 0.f, 0.f);
        float4 a1 = make_float4(0.f, 0.f, 0.f, 0.f);
        if (okA) {
            a0 = X4[(size_t)arow * 32 + kstep * 8 + quad * 2];
            a1 = X4[(size_t)arow * 32 + kstep * 8 + quad * 2 + 1];
        }
        float av8[8] = {a0.x, a0.y, a0.z, a0.w, a1.x, a1.y, a1.z, a1.w};
        bf16x8 ah, al;
#pragma unroll
        for (int j = 0; j < 8; ++j) {
            unsigned short h = bf16_rne(av8[j]);
            ah[j] = (short)h;
            al[j] = (short)bf16_rne(av8[j] - bf16_tof(h));
        }
#pragma unroll
        for (int ct = 0; ct < 8; ++ct) {
            size_t boff = ((size_t)(kstep * 8 + ct) * 64 + l) * 8;
            bf16x8 bh = *(const bf16x8*)(wf_hi + boff);
            bf16x8 bl = *(const bf16x8*)(wf_lo + boff);
            acc[ct] = __builtin_amdgcn_mfma_f32_16x16x32_bf16(ah, bh, acc[ct], 0, 0, 0);
            acc[ct] = __builtin_amdgcn_mfma_f32_16x16x32_bf16(al, bh, acc[ct], 0, 0, 0);
            acc[ct] = __builtin_amdgcn_mfma_f32_16x16x32_bf16(ah, bl, acc[ct], 0, 0, 0);
        }
    }

    // store h: lane holds col = ct*16+m, rows row0+quad*4+reg
#pragma unroll
    for (int reg = 0; reg < 4; ++reg) {
        int row = row0 + quad * 4 + reg;
        if (row < N) {
#pragma unroll
            for (int ct = 0; ct < 8; ++ct)
                Hout[(size_t)row * 128 + ct * 16 + m] = acc[ct][reg];
        }
    }

    // fused alpha: a-vec value for this lane's cols
    float av[8], dv[8];
#pragma unroll
    for (int ct = 0; ct < 8; ++ct) {
        av[ct] = asrc[ct * 16 + m];
        dv[ct] = adst[ct * 16 + m];
    }
#pragma unroll
    for (int reg = 0; reg < 4; ++reg) {
        int row = row0 + quad * 4 + reg;
        if (H == 4) {
            float ps[4], pd[4];
#pragma unroll
            for (int hh = 0; hh < 4; ++hh) {
                ps[hh] = acc[2 * hh][reg] * av[2 * hh] +
                         acc[2 * hh + 1][reg] * av[2 * hh + 1];
                pd[hh] = acc[2 * hh][reg] * dv[2 * hh] +
                         acc[2 * hh + 1][reg] * dv[2 * hh + 1];
            }
#pragma unroll
            for (int o = 1; o < 16; o <<= 1) {
#pragma unroll
                for (int hh = 0; hh < 4; ++hh) {
                    ps[hh] += __shfl_xor(ps[hh], o);
                    pd[hh] += __shfl_xor(pd[hh], o);
                }
            }
            if (m == 0 && row < N) {
#pragma unroll
                for (int hh = 0; hh < 4; ++hh) {
                    alpha_s[(size_t)row * 4 + hh] = ps[hh];
                    alpha_d[(size_t)row * 4 + hh] = pd[hh];
                }
            }
        } else {
            float ps = 0.f, pd = 0.f;
#pragma unroll
            for (int ct = 0; ct < 8; ++ct) {
                ps += acc[ct][reg] * av[ct];
                pd += acc[ct][reg] * dv[ct];
            }
#pragma unroll
            for (int o = 1; o < 16; o <<= 1) {
                ps += __shfl_xor(ps, o);
                pd += __shfl_xor(pd, o);
            }
            if (m == 0 && row < N) {
                alpha_s[row] = ps;
                alpha_d[row] = pd;
            }
        }
    }
}

// ---------------------------------------------------------------------------
// Segment softmax + aggregation from the bucket table (R8 version: x8 MLP
// unroll — measured best). Two nodes per wave (32 lanes each).
// ---------------------------------------------------------------------------
template <int H>
__global__ __launch_bounds__(128) void gather_kernel(
    const float* __restrict__ h, const float* __restrict__ as_,
    const float* __restrict__ ad_, const int* __restrict__ cnt,
    const int* __restrict__ bucket, const int* __restrict__ ovf_src,
    const int* __restrict__ ovf_dst, const int* __restrict__ ovf_cnt,
    const float* __restrict__ bias, float* __restrict__ out, int N) {
    __shared__ int s_src[4][32];
    __shared__ float s_w[4][32 * H];
    int t = threadIdx.x;
    int wv = t >> 6;
    int lane = t & 63;
    int hw = lane >> 5;
    int l = lane & 31;
    int sub = wv * 2 + hw;
    int n = blockIdx.x * 4 + sub;
    if (n >= N) return;

    int deg = cnt[n];
    int total = deg + 1;
    int totalb = min(deg, CAP) + 1;
    int onum = (deg > CAP) ? *ovf_cnt : 0;
    const int* bk = bucket + (size_t)n * CAP;

    float adv[H];
#pragma unroll
    for (int hh = 0; hh < H; ++hh) adv[hh] = ad_[(size_t)n * H + hh];

    float sv[H];
    float m[H];
#pragma unroll
    for (int hh = 0; hh < H; ++hh) m[hh] = -3.4e38f;
    int total0 = min(total, 32);
    if (l < total0) {
        int src = (l == 0) ? n : bk[l - 1];
        s_src[sub][l] = src;
        if (H == 4) {
            float4 a4 = ((const float4*)as_)[src];
            sv[0] = a4.x + adv[0];
            sv[1] = a4.y + adv[1];
            sv[2] = a4.z + adv[2];
            sv[3] = a4.w + adv[3];
        } else {
            sv[0] = as_[src] + adv[0];
        }
#pragma unroll
        for (int hh = 0; hh < H; ++hh) {
            float s = sv[hh];
            s = (s > 0.f) ? s : NEG_SLOPE * s;
            sv[hh] = s;
            m[hh] = s;
        }
    }
    for (int idx = l + 32; idx < totalb; idx += 32) {
        int src = bk[idx - 1];
#pragma unroll
        for (int hh = 0; hh < H; ++hh) {
            float s = as_[(size_t)src * H + hh] + adv[hh];
            s = (s > 0.f) ? s : NEG_SLOPE * s;
            m[hh] = fmaxf(m[hh], s);
        }
    }
    for (int e = 0; e < onum; ++e) {
        if (ovf_dst[e] == n && l == 0) {
            int src = ovf_src[e];
#pragma unroll
            for (int hh = 0; hh < H; ++hh) {
                float s = as_[(size_t)src * H + hh] + adv[hh];
                s = (s > 0.f) ? s : NEG_SLOPE * s;
                m[hh] = fmaxf(m[hh], s);
            }
        }
    }
#pragma unroll
    for (int o = 16; o > 0; o >>= 1)
#pragma unroll
        for (int hh = 0; hh < H; ++hh) m[hh] = fmaxf(m[hh], __shfl_xor(m[hh], o));

    float p[H];
    float dsum[H];
#pragma unroll
    for (int hh = 0; hh < H; ++hh) dsum[hh] = 0.f;
    if (l < total0) {
#pragma unroll
        for (int hh = 0; hh < H; ++hh) {
            p[hh] = __expf(sv[hh] - m[hh]);
            dsum[hh] = p[hh];
        }
    }
    for (int idx = l + 32; idx < totalb; idx += 32) {
        int src = bk[idx - 1];
#pragma unroll
        for (int hh = 0; hh < H; ++hh) {
            float s = as_[(size_t)src * H + hh] + adv[hh];
            s = (s > 0.f) ? s : NEG_SLOPE * s;
            dsum[hh] += __expf(s - m[hh]);
        }
    }
    for (int e = 0; e < onum; ++e) {
        if (ovf_dst[e] == n && l == 0) {
            int src = ovf_src[e];
#pragma unroll
            for (int hh = 0; hh < H; ++hh) {
                float s = as_[(size_t)src * H + hh] + adv[hh];
                s = (s > 0.f) ? s : NEG_SLOPE * s;
                dsum[hh] += __expf(s - m[hh]);
            }
        }
    }
#pragma unroll
    for (int o = 16; o > 0; o >>= 1)
#pragma unroll
        for (int hh = 0; hh < H; ++hh) dsum[hh] += __shfl_xor(dsum[hh], o);
    float inv[H];
#pragma unroll
    for (int hh = 0; hh < H; ++hh) inv[hh] = 1.f / dsum[hh];

    if (l < total0) {
#pragma unroll
        for (int hh = 0; hh < H; ++hh) s_w[sub][l * H + hh] = p[hh] * inv[hh];
    }

    const int head_t = (H == 1) ? 0 : (l >> 3);
    float4 acc = make_float4(0.f, 0.f, 0.f, 0.f);
    const float4* __restrict__ h4 = (const float4*)h;
    for (int base = 0; base < totalb; base += 32) {
        int cnt2 = min(32, totalb - base);
        if (base > 0 && l < cnt2) {
            int src = bk[base + l - 1];
            s_src[sub][l] = src;
#pragma unroll
            for (int hh = 0; hh < H; ++hh) {
                float s = as_[(size_t)src * H + hh] + adv[hh];
                s = (s > 0.f) ? s : NEG_SLOPE * s;
                s_w[sub][l * H + hh] = __expf(s - m[hh]) * inv[hh];
            }
        }
        __builtin_amdgcn_wave_barrier();
        int j = 0;
        for (; j + 8 <= cnt2; j += 8) {
            int ts[8];
            float ws[8];
            float4 vs[8];
#pragma unroll
            for (int u = 0; u < 8; ++u) {
                ts[u] = s_src[sub][j + u];
                ws[u] = s_w[sub][(j + u) * H + head_t];
            }
#pragma unroll
            for (int u = 0; u < 8; ++u) vs[u] = h4[(size_t)ts[u] * 32 + l];
#pragma unroll
            for (int u = 0; u < 8; ++u) {
                acc.x += ws[u] * vs[u].x;
                acc.y += ws[u] * vs[u].y;
                acc.z += ws[u] * vs[u].z;
                acc.w += ws[u] * vs[u].w;
            }
        }
        for (; j + 4 <= cnt2; j += 4) {
            int ts[4];
            float ws[4];
            float4 vs[4];
#pragma unroll
            for (int u = 0; u < 4; ++u) {
                ts[u] = s_src[sub][j + u];
                ws[u] = s_w[sub][(j + u) * H + head_t];
            }
#pragma unroll
            for (int u = 0; u < 4; ++u) vs[u] = h4[(size_t)ts[u] * 32 + l];
#pragma unroll
            for (int u = 0; u < 4; ++u) {
                acc.x += ws[u] * vs[u].x;
                acc.y += ws[u] * vs[u].y;
                acc.z += ws[u] * vs[u].z;
                acc.w += ws[u] * vs[u].w;
            }
        }
        for (; j < cnt2; ++j) {
            int sj = s_src[sub][j];
            float wj = s_w[sub][j * H + head_t];
            float4 hv = h4[(size_t)sj * 32 + l];
            acc.x += wj * hv.x; acc.y += wj * hv.y;
            acc.z += wj * hv.z; acc.w += wj * hv.w;
        }
        __builtin_amdgcn_wave_barrier();
    }
    for (int e = 0; e < onum; ++e) {
        if (ovf_dst[e] == n) {
            int src = ovf_src[e];
            int hh = head_t;
            float s = as_[(size_t)src * H + hh] + adv[hh];
            s = (s > 0.f) ? s : NEG_SLOPE * s;
            float wj = __expf(s - m[hh]) * inv[hh];
            float4 hv = h4[(size_t)src * 32 + l];
            acc.x += wj * hv.x; acc.y += wj * hv.y;
            acc.z += wj * hv.z; acc.w += wj * hv.w;
        }
    }
    float4 bv = ((const float4*)bias)[l];
    float4 o4;
    o4.x = fmaxf(acc.x + bv.x, 0.f);
    o4.y = fmaxf(acc.y + bv.y, 0.f);
    o4.z = fmaxf(acc.z + bv.z, 0.f);
    o4.w = fmaxf(acc.w + bv.w, 0.f);
    ((float4*)out)[(size_t)n * 32 + l] = o4;
}

// ---------------------------------------------------------------------------
extern "C" void kernel_launch(void* const* d_in, const int* in_sizes, int n_in,
                              void* d_out, int out_size, void* d_ws,
                              size_t ws_size, hipStream_t stream) {
    const float* x   = (const float*)d_in[0];
    const void*  ei  = d_in[1];
    const float* W0  = (const float*)d_in[2];
    const float* as0 = (const float*)d_in[3];
    const float* ad0 = (const float*)d_in[4];
    const float* b0  = (const float*)d_in[5];
    const float* W1  = (const float*)d_in[6];
    const float* as1 = (const float*)d_in[7];
    const float* ad1 = (const float*)d_in[8];
    const float* b1  = (const float*)d_in[9];
    const float* W2  = (const float*)d_in[10];
    const float* as2 = (const float*)d_in[11];
    const float* ad2 = (const float*)d_in[12];
    const float* b2  = (const float*)d_in[13];

    int N = in_sizes[0] / 128;
    int E = in_sizes[1] / 2;
    float* out = (float*)d_out;

    // workspace layout (~47.3 MB)
    float* h       = (float*)d_ws;                       // N*128
    float* alpha_s = h + (size_t)N * 128;                // N*4 (max H)
    float* alpha_d = alpha_s + (size_t)N * 4;            // N*4
    int*   cnt     = (int*)(alpha_d + (size_t)N * 4);    // N
    int*   ovf_c   = cnt + N;                            // 1
    int*   bucket  = ovf_c + 1;                          // N*CAP
    int*   ovf_src = bucket + (size_t)N * CAP;           // E
    int*   ovf_dst = ovf_src + E;                        // E
    unsigned short* wf = (unsigned short*)(ovf_dst + E); // 3*32768 ushort

    int eb = (E + 255) / 256;
    int nb = (N + 1 + 255) / 256;

    zero_kernel<<<nb, 256, 0, stream>>>(cnt, N + 1);
    wprep_kernel<<<24, 256, 0, stream>>>(W0, W1, W2, wf);
    build_kernel<<<eb, 256, 0, stream>>>(ei, E, cnt, bucket, ovf_src, ovf_dst, ovf_c);

    int gb = (N + 63) / 64;
    int wb = (N + 3) / 4;

    // layer 0: H=4
    gemm_mfma_kernel<4><<<gb, 256, 0, stream>>>(x, wf, wf + 16384, as0, ad0,
                                                h, alpha_s, alpha_d, N);
    gather_kernel<4><<<wb, 128, 0, stream>>>(h, alpha_s, alpha_d, cnt, bucket,
                                             ovf_src, ovf_dst, ovf_c, b0, out, N);

    // layer 1: H=4
    gemm_mfma_kernel<4><<<gb, 256, 0, stream>>>(out, wf + 32768, wf + 49152,
                                                as1, ad1, h, alpha_s, alpha_d, N);
    gather_kernel<4><<<wb, 128, 0, stream>>>(h, alpha_s, alpha_d, cnt, bucket,
                                             ovf_src, ovf_dst, ovf_c, b1, out, N);

    // layer 2: H=1
    gemm_mfma_kernel<1><<<gb, 256, 0, stream>>>(out, wf + 65536, wf + 81920,
                                                as2, ad2, h, alpha_s, alpha_d, N);
    gather_kernel<1><<<wb, 128, 0, stream>>>(h, alpha_s, alpha_d, cnt, bucket,
                                             ovf_src, ovf_dst, ovf_c, b2, out, N);
}

// Round 11
// 362.230 us; speedup vs baseline: 1.2490x; 1.1288x over previous
//
#include <hip/hip_runtime.h>

#define NEG_SLOPE 0.2f
#define CAP 64  // bucket capacity per node; overflow handled exactly

using f32x4 = __attribute__((ext_vector_type(4))) float;
using bf16x8 = __attribute__((ext_vector_type(8))) short;

__device__ inline unsigned short bf16_rne(float f) {
    unsigned int u = __float_as_uint(f);
    return (unsigned short)((u + 0x7FFF + ((u >> 16) & 1)) >> 16);
}
__device__ inline float bf16_tof(unsigned short h) {
    return __uint_as_float(((unsigned int)h) << 16);
}

// ---------------------------------------------------------------------------
// prep: wprep (first 24 blocks) + zero cnt/ovf (rest). Independent tasks.
// wf layout per layer (32768 ushort): hi[(kstep*8+ct)*64+lane][8j], lo +16384.
// B-frag element: W[k=kstep*32+(lane>>4)*8+j][n=ct*16+(lane&15)].
// ---------------------------------------------------------------------------
__global__ void prep_kernel(const float* __restrict__ W0,
                            const float* __restrict__ W1,
                            const float* __restrict__ W2,
                            unsigned short* __restrict__ wf,
                            int* __restrict__ cnt, int nz) {
    if (blockIdx.x < 24) {
        int tid = blockIdx.x * 256 + threadIdx.x;  // 0..6143
        if (tid >= 3 * 2048) return;
        int layer = tid >> 11;
        int rem = tid & 2047;
        int kstep = rem >> 9;
        int ct = (rem >> 6) & 7;
        int lane = rem & 63;
        const float* W = (layer == 0) ? W0 : (layer == 1) ? W1 : W2;
        unsigned short* hi = wf + (size_t)layer * 32768 +
                             ((size_t)(kstep * 8 + ct) * 64 + lane) * 8;
        unsigned short* lo = hi + 16384;
#pragma unroll
        for (int j = 0; j < 8; ++j) {
            int k = kstep * 32 + (lane >> 4) * 8 + j;
            int n = ct * 16 + (lane & 15);
            float f = W[k * 128 + n];
            unsigned short h = bf16_rne(f);
            hi[j] = h;
            lo[j] = bf16_rne(f - bf16_tof(h));
        }
    } else {
        int i = (blockIdx.x - 24) * 256 + threadIdx.x;
        if (i < nz) cnt[i] = 0;
    }
}

// ---------------------------------------------------------------------------
// build body: one edge per thread; bucket by dst, exact overflow spill.
// ---------------------------------------------------------------------------
__device__ inline void build_body(int i, const void* __restrict__ ei_raw,
                                  int E, int* __restrict__ cnt,
                                  int* __restrict__ bucket,
                                  int* __restrict__ ovf_src,
                                  int* __restrict__ ovf_dst,
                                  int* __restrict__ ovf_cnt) {
    const int* as32 = (const int*)ei_raw;
    const long long* as64 = (const long long*)ei_raw;
    bool is64 = true;
    for (int k = 0; k < 16; ++k) {
        long long v = as64[k];
        if (!(v >= 0 && v < 2147483648LL)) { is64 = false; }
    }
    if (i < E) {
        int s, d;
        if (is64) {
            s = (int)as64[i];
            d = (int)as64[(size_t)E + i];
        } else {
            s = as32[i];
            d = as32[(size_t)E + i];
        }
        int p = atomicAdd(&cnt[d], 1);
        if (p < CAP) {
            bucket[(size_t)d * CAP + p] = s;
        } else {
            int q = atomicAdd(ovf_cnt, 1);
            ovf_src[q] = s;
            ovf_dst[q] = d;
        }
    }
}

// ---------------------------------------------------------------------------
// Split-bf16 MFMA GEMM body + fused alpha epilogue. 4 waves/block; wave =
// 16 rows x 128 cols; 8 col-tiles of 16x16x32; K=128 in 4 steps.
// C = Ahi*Bhi + Alo*Bhi + Ahi*Blo. C/D: col=lane&15, row=(lane>>4)*4+reg.
// BF16OUT: h stored as bf16 (ushort) for the traffic-halved gather.
// ---------------------------------------------------------------------------
template <int H, bool BF16OUT>
__device__ inline void gemm_body(int bid, const float* __restrict__ X,
                                 const unsigned short* __restrict__ wf_hi,
                                 const unsigned short* __restrict__ wf_lo,
                                 const float* __restrict__ asrc,
                                 const float* __restrict__ adst,
                                 void* __restrict__ Hout,
                                 float* __restrict__ alpha_s,
                                 float* __restrict__ alpha_d, int N) {
    int t = threadIdx.x;
    int wv = t >> 6;
    int l = t & 63;
    int m = l & 15;
    int quad = l >> 4;
    int row0 = bid * 64 + wv * 16;

    f32x4 acc[8];
#pragma unroll
    for (int ct = 0; ct < 8; ++ct) acc[ct] = (f32x4){0.f, 0.f, 0.f, 0.f};

    int arow = row0 + m;
    bool okA = arow < N;
    const float4* X4 = (const float4*)X;

    for (int kstep = 0; kstep < 4; ++kstep) {
        float4 a0 = make_float4(0.f, 0.f, 0.f, 0.f);
        float4 a1 = make_float4(0.f, 0.f, 0.f, 0.f);
        if (okA) {
            a0 = X4[(size_t)arow * 32 + kstep * 8 + quad * 2];
            a1 = X4[(size_t)arow * 32 + kstep * 8 + quad * 2 + 1];
        }
        float av8[8] = {a0.x, a0.y, a0.z, a0.w, a1.x, a1.y, a1.z, a1.w};
        bf16x8 ah, al;
#pragma unroll
        for (int j = 0; j < 8; ++j) {
            unsigned short h = bf16_rne(av8[j]);
            ah[j] = (short)h;
            al[j] = (short)bf16_rne(av8[j] - bf16_tof(h));
        }
#pragma unroll
        for (int ct = 0; ct < 8; ++ct) {
            size_t boff = ((size_t)(kstep * 8 + ct) * 64 + l) * 8;
            bf16x8 bh = *(const bf16x8*)(wf_hi + boff);
            bf16x8 bl = *(const bf16x8*)(wf_lo + boff);
            acc[ct] = __builtin_amdgcn_mfma_f32_16x16x32_bf16(ah, bh, acc[ct], 0, 0, 0);
            acc[ct] = __builtin_amdgcn_mfma_f32_16x16x32_bf16(al, bh, acc[ct], 0, 0, 0);
            acc[ct] = __builtin_amdgcn_mfma_f32_16x16x32_bf16(ah, bl, acc[ct], 0, 0, 0);
        }
    }

    // store h
#pragma unroll
    for (int reg = 0; reg < 4; ++reg) {
        int row = row0 + quad * 4 + reg;
        if (row < N) {
            if (BF16OUT) {
                unsigned short* hb = (unsigned short*)Hout;
#pragma unroll
                for (int ct = 0; ct < 8; ++ct)
                    hb[(size_t)row * 128 + ct * 16 + m] = bf16_rne(acc[ct][reg]);
            } else {
                float* hf = (float*)Hout;
#pragma unroll
                for (int ct = 0; ct < 8; ++ct)
                    hf[(size_t)row * 128 + ct * 16 + m] = acc[ct][reg];
            }
        }
    }

    // fused alpha
    float av[8], dv[8];
#pragma unroll
    for (int ct = 0; ct < 8; ++ct) {
        av[ct] = asrc[ct * 16 + m];
        dv[ct] = adst[ct * 16 + m];
    }
#pragma unroll
    for (int reg = 0; reg < 4; ++reg) {
        int row = row0 + quad * 4 + reg;
        if (H == 4) {
            float ps[4], pd[4];
#pragma unroll
            for (int hh = 0; hh < 4; ++hh) {
                ps[hh] = acc[2 * hh][reg] * av[2 * hh] +
                         acc[2 * hh + 1][reg] * av[2 * hh + 1];
                pd[hh] = acc[2 * hh][reg] * dv[2 * hh] +
                         acc[2 * hh + 1][reg] * dv[2 * hh + 1];
            }
#pragma unroll
            for (int o = 1; o < 16; o <<= 1) {
#pragma unroll
                for (int hh = 0; hh < 4; ++hh) {
                    ps[hh] += __shfl_xor(ps[hh], o);
                    pd[hh] += __shfl_xor(pd[hh], o);
                }
            }
            if (m == 0 && row < N) {
#pragma unroll
                for (int hh = 0; hh < 4; ++hh) {
                    alpha_s[(size_t)row * 4 + hh] = ps[hh];
                    alpha_d[(size_t)row * 4 + hh] = pd[hh];
                }
            }
        } else {
            float ps = 0.f, pd = 0.f;
#pragma unroll
            for (int ct = 0; ct < 8; ++ct) {
                ps += acc[ct][reg] * av[ct];
                pd += acc[ct][reg] * dv[ct];
            }
#pragma unroll
            for (int o = 1; o < 16; o <<= 1) {
                ps += __shfl_xor(ps, o);
                pd += __shfl_xor(pd, o);
            }
            if (m == 0 && row < N) {
                alpha_s[row] = ps;
                alpha_d[row] = pd;
            }
        }
    }
}

// Fused layer-0 gemm + adjacency build (independent work; build is pure
// latency — overlaps under the gemm's compute per m114 co-scheduling).
template <int H, bool BF16OUT>
__global__ __launch_bounds__(256) void gemm_build_kernel(
    const float* __restrict__ X, const unsigned short* __restrict__ wf_hi,
    const unsigned short* __restrict__ wf_lo, const float* __restrict__ asrc,
    const float* __restrict__ adst, void* __restrict__ Hout,
    float* __restrict__ alpha_s, float* __restrict__ alpha_d, int N, int gb,
    const void* __restrict__ ei_raw, int E, int* __restrict__ cnt,
    int* __restrict__ bucket, int* __restrict__ ovf_src,
    int* __restrict__ ovf_dst, int* __restrict__ ovf_cnt) {
    if ((int)blockIdx.x < gb) {
        gemm_body<H, BF16OUT>(blockIdx.x, X, wf_hi, wf_lo, asrc, adst, Hout,
                              alpha_s, alpha_d, N);
    } else {
        int i = ((int)blockIdx.x - gb) * 256 + threadIdx.x;
        build_body(i, ei_raw, E, cnt, bucket, ovf_src, ovf_dst, ovf_cnt);
    }
}

template <int H, bool BF16OUT>
__global__ __launch_bounds__(256) void gemm_kernel(
    const float* __restrict__ X, const unsigned short* __restrict__ wf_hi,
    const unsigned short* __restrict__ wf_lo, const float* __restrict__ asrc,
    const float* __restrict__ adst, void* __restrict__ Hout,
    float* __restrict__ alpha_s, float* __restrict__ alpha_d, int N) {
    gemm_body<H, BF16OUT>(blockIdx.x, X, wf_hi, wf_lo, asrc, adst, Hout,
                          alpha_s, alpha_d, N);
}

// ---------------------------------------------------------------------------
// Segment softmax + aggregation from the bucket table. Two nodes per wave
// (32 lanes each); x8 MLP unroll (measured best, R8). BF16IN: h rows are
// bf16-packed (8B/lane) — halves the dominant gather traffic.
// ---------------------------------------------------------------------------
template <int H, bool BF16IN>
__global__ __launch_bounds__(128) void gather_kernel(
    const void* __restrict__ hvp, const float* __restrict__ as_,
    const float* __restrict__ ad_, const int* __restrict__ cnt,
    const int* __restrict__ bucket, const int* __restrict__ ovf_src,
    const int* __restrict__ ovf_dst, const int* __restrict__ ovf_cnt,
    const float* __restrict__ bias, float* __restrict__ out, int N) {
    __shared__ int s_src[4][32];
    __shared__ float s_w[4][32 * H];
    int t = threadIdx.x;
    int wv = t >> 6;
    int lane = t & 63;
    int hw = lane >> 5;
    int l = lane & 31;
    int sub = wv * 2 + hw;
    int n = blockIdx.x * 4 + sub;
    if (n >= N) return;

    int deg = cnt[n];
    int total = deg + 1;
    int totalb = min(deg, CAP) + 1;
    int onum = (deg > CAP) ? *ovf_cnt : 0;
    const int* bk = bucket + (size_t)n * CAP;

    float adv[H];
#pragma unroll
    for (int hh = 0; hh < H; ++hh) adv[hh] = ad_[(size_t)n * H + hh];

    float sv[H];
    float m[H];
#pragma unroll
    for (int hh = 0; hh < H; ++hh) m[hh] = -3.4e38f;
    int total0 = min(total, 32);
    if (l < total0) {
        int src = (l == 0) ? n : bk[l - 1];
        s_src[sub][l] = src;
        if (H == 4) {
            float4 a4 = ((const float4*)as_)[src];
            sv[0] = a4.x + adv[0];
            sv[1] = a4.y + adv[1];
            sv[2] = a4.z + adv[2];
            sv[3] = a4.w + adv[3];
        } else {
            sv[0] = as_[src] + adv[0];
        }
#pragma unroll
        for (int hh = 0; hh < H; ++hh) {
            float s = sv[hh];
            s = (s > 0.f) ? s : NEG_SLOPE * s;
            sv[hh] = s;
            m[hh] = s;
        }
    }
    for (int idx = l + 32; idx < totalb; idx += 32) {
        int src = bk[idx - 1];
#pragma unroll
        for (int hh = 0; hh < H; ++hh) {
            float s = as_[(size_t)src * H + hh] + adv[hh];
            s = (s > 0.f) ? s : NEG_SLOPE * s;
            m[hh] = fmaxf(m[hh], s);
        }
    }
    for (int e = 0; e < onum; ++e) {
        if (ovf_dst[e] == n && l == 0) {
            int src = ovf_src[e];
#pragma unroll
            for (int hh = 0; hh < H; ++hh) {
                float s = as_[(size_t)src * H + hh] + adv[hh];
                s = (s > 0.f) ? s : NEG_SLOPE * s;
                m[hh] = fmaxf(m[hh], s);
            }
        }
    }
#pragma unroll
    for (int o = 16; o > 0; o >>= 1)
#pragma unroll
        for (int hh = 0; hh < H; ++hh) m[hh] = fmaxf(m[hh], __shfl_xor(m[hh], o));

    float p[H];
    float dsum[H];
#pragma unroll
    for (int hh = 0; hh < H; ++hh) dsum[hh] = 0.f;
    if (l < total0) {
#pragma unroll
        for (int hh = 0; hh < H; ++hh) {
            p[hh] = __expf(sv[hh] - m[hh]);
            dsum[hh] = p[hh];
        }
    }
    for (int idx = l + 32; idx < totalb; idx += 32) {
        int src = bk[idx - 1];
#pragma unroll
        for (int hh = 0; hh < H; ++hh) {
            float s = as_[(size_t)src * H + hh] + adv[hh];
            s = (s > 0.f) ? s : NEG_SLOPE * s;
            dsum[hh] += __expf(s - m[hh]);
        }
    }
    for (int e = 0; e < onum; ++e) {
        if (ovf_dst[e] == n && l == 0) {
            int src = ovf_src[e];
#pragma unroll
            for (int hh = 0; hh < H; ++hh) {
                float s = as_[(size_t)src * H + hh] + adv[hh];
                s = (s > 0.f) ? s : NEG_SLOPE * s;
                dsum[hh] += __expf(s - m[hh]);
            }
        }
    }
#pragma unroll
    for (int o = 16; o > 0; o >>= 1)
#pragma unroll
        for (int hh = 0; hh < H; ++hh) dsum[hh] += __shfl_xor(dsum[hh], o);
    float inv[H];
#pragma unroll
    for (int hh = 0; hh < H; ++hh) inv[hh] = 1.f / dsum[hh];

    if (l < total0) {
#pragma unroll
        for (int hh = 0; hh < H; ++hh) s_w[sub][l * H + hh] = p[hh] * inv[hh];
    }

    const int head_t = (H == 1) ? 0 : (l >> 3);
    float4 acc = make_float4(0.f, 0.f, 0.f, 0.f);
    const float4* __restrict__ h4 = (const float4*)hvp;
    const uint2* __restrict__ hb2 = (const uint2*)hvp;
    for (int base = 0; base < totalb; base += 32) {
        int cnt2 = min(32, totalb - base);
        if (base > 0 && l < cnt2) {
            int src = bk[base + l - 1];
            s_src[sub][l] = src;
#pragma unroll
            for (int hh = 0; hh < H; ++hh) {
                float s = as_[(size_t)src * H + hh] + adv[hh];
                s = (s > 0.f) ? s : NEG_SLOPE * s;
                s_w[sub][l * H + hh] = __expf(s - m[hh]) * inv[hh];
            }
        }
        __builtin_amdgcn_wave_barrier();
        int j = 0;
        for (; j + 8 <= cnt2; j += 8) {
            int ts[8];
            float ws[8];
#pragma unroll
            for (int u = 0; u < 8; ++u) {
                ts[u] = s_src[sub][j + u];
                ws[u] = s_w[sub][(j + u) * H + head_t];
            }
            if (BF16IN) {
                uint2 rv[8];
#pragma unroll
                for (int u = 0; u < 8; ++u) rv[u] = hb2[(size_t)ts[u] * 32 + l];
#pragma unroll
                for (int u = 0; u < 8; ++u) {
                    acc.x += ws[u] * __uint_as_float(rv[u].x << 16);
                    acc.y += ws[u] * __uint_as_float(rv[u].x & 0xFFFF0000u);
                    acc.z += ws[u] * __uint_as_float(rv[u].y << 16);
                    acc.w += ws[u] * __uint_as_float(rv[u].y & 0xFFFF0000u);
                }
            } else {
                float4 vs[8];
#pragma unroll
                for (int u = 0; u < 8; ++u) vs[u] = h4[(size_t)ts[u] * 32 + l];
#pragma unroll
                for (int u = 0; u < 8; ++u) {
                    acc.x += ws[u] * vs[u].x;
                    acc.y += ws[u] * vs[u].y;
                    acc.z += ws[u] * vs[u].z;
                    acc.w += ws[u] * vs[u].w;
                }
            }
        }
        for (; j < cnt2; ++j) {
            int sj = s_src[sub][j];
            float wj = s_w[sub][j * H + head_t];
            if (BF16IN) {
                uint2 rv = hb2[(size_t)sj * 32 + l];
                acc.x += wj * __uint_as_float(rv.x << 16);
                acc.y += wj * __uint_as_float(rv.x & 0xFFFF0000u);
                acc.z += wj * __uint_as_float(rv.y << 16);
                acc.w += wj * __uint_as_float(rv.y & 0xFFFF0000u);
            } else {
                float4 hv = h4[(size_t)sj * 32 + l];
                acc.x += wj * hv.x; acc.y += wj * hv.y;
                acc.z += wj * hv.z; acc.w += wj * hv.w;
            }
        }
        __builtin_amdgcn_wave_barrier();
    }
    for (int e = 0; e < onum; ++e) {
        if (ovf_dst[e] == n) {
            int src = ovf_src[e];
            int hh = head_t;
            float s = as_[(size_t)src * H + hh] + adv[hh];
            s = (s > 0.f) ? s : NEG_SLOPE * s;
            float wj = __expf(s - m[hh]) * inv[hh];
            if (BF16IN) {
                uint2 rv = hb2[(size_t)src * 32 + l];
                acc.x += wj * __uint_as_float(rv.x << 16);
                acc.y += wj * __uint_as_float(rv.x & 0xFFFF0000u);
                acc.z += wj * __uint_as_float(rv.y << 16);
                acc.w += wj * __uint_as_float(rv.y & 0xFFFF0000u);
            } else {
                float4 hv = h4[(size_t)src * 32 + l];
                acc.x += wj * hv.x; acc.y += wj * hv.y;
                acc.z += wj * hv.z; acc.w += wj * hv.w;
            }
        }
    }
    float4 bv = ((const float4*)bias)[l];
    float4 o4;
    o4.x = fmaxf(acc.x + bv.x, 0.f);
    o4.y = fmaxf(acc.y + bv.y, 0.f);
    o4.z = fmaxf(acc.z + bv.z, 0.f);
    o4.w = fmaxf(acc.w + bv.w, 0.f);
    ((float4*)out)[(size_t)n * 32 + l] = o4;
}

// ---------------------------------------------------------------------------
extern "C" void kernel_launch(void* const* d_in, const int* in_sizes, int n_in,
                              void* d_out, int out_size, void* d_ws,
                              size_t ws_size, hipStream_t stream) {
    const float* x   = (const float*)d_in[0];
    const void*  ei  = d_in[1];
    const float* W0  = (const float*)d_in[2];
    const float* as0 = (const float*)d_in[3];
    const float* ad0 = (const float*)d_in[4];
    const float* b0  = (const float*)d_in[5];
    const float* W1  = (const float*)d_in[6];
    const float* as1 = (const float*)d_in[7];
    const float* ad1 = (const float*)d_in[8];
    const float* b1  = (const float*)d_in[9];
    const float* W2  = (const float*)d_in[10];
    const float* as2 = (const float*)d_in[11];
    const float* ad2 = (const float*)d_in[12];
    const float* b2  = (const float*)d_in[13];

    int N = in_sizes[0] / 128;
    int E = in_sizes[1] / 2;
    float* out = (float*)d_out;

    // workspace layout (~47.3 MB). h region is fp32-sized; layers 0/1 use it
    // as bf16 (first half), layer 2 as fp32 — never concurrently live.
    float* h       = (float*)d_ws;                       // N*128 f32
    float* alpha_s = h + (size_t)N * 128;                // N*4 (max H)
    float* alpha_d = alpha_s + (size_t)N * 4;            // N*4
    int*   cnt     = (int*)(alpha_d + (size_t)N * 4);    // N
    int*   ovf_c   = cnt + N;                            // 1
    int*   bucket  = ovf_c + 1;                          // N*CAP
    int*   ovf_src = bucket + (size_t)N * CAP;           // E
    int*   ovf_dst = ovf_src + E;                        // E
    unsigned short* wf = (unsigned short*)(ovf_dst + E); // 3*32768 ushort

    int eb = (E + 255) / 256;
    int nb = (N + 1 + 255) / 256;
    int gb = (N + 63) / 64;
    int wb = (N + 3) / 4;

    // prep: wprep (24 blocks) + zero cnt/ovf counter
    prep_kernel<<<24 + nb, 256, 0, stream>>>(W0, W1, W2, wf, cnt, N + 1);

    // layer 0 gemm fused with adjacency build
    gemm_build_kernel<4, true><<<gb + eb, 256, 0, stream>>>(
        x, wf, wf + 16384, as0, ad0, h, alpha_s, alpha_d, N, gb,
        ei, E, cnt, bucket, ovf_src, ovf_dst, ovf_c);
    gather_kernel<4, true><<<wb, 128, 0, stream>>>(h, alpha_s, alpha_d, cnt,
                                                   bucket, ovf_src, ovf_dst,
                                                   ovf_c, b0, out, N);

    // layer 1
    gemm_kernel<4, true><<<gb, 256, 0, stream>>>(out, wf + 32768, wf + 49152,
                                                 as1, ad1, h, alpha_s, alpha_d, N);
    gather_kernel<4, true><<<wb, 128, 0, stream>>>(h, alpha_s, alpha_d, cnt,
                                                   bucket, ovf_src, ovf_dst,
                                                   ovf_c, b1, out, N);

    // layer 2 (H=1, fp32 h — final aggregation kept full precision)
    gemm_kernel<1, false><<<gb, 256, 0, stream>>>(out, wf + 65536, wf + 81920,
                                                  as2, ad2, h, alpha_s, alpha_d, N);
    gather_kernel<1, false><<<wb, 128, 0, stream>>>(h, alpha_s, alpha_d, cnt,
                                                    bucket, ovf_src, ovf_dst,
                                                    ovf_c, b2, out, N);
}